// Round 18
// baseline (217.757 us; speedup 1.0000x reference)
//
#include <hip/hip_runtime.h>

using i32x4  = __attribute__((ext_vector_type(4))) int;
using i32x16 = __attribute__((ext_vector_type(16))) int;

constexpr int K_DIM = 4096;   // N_IN
constexpr int N_DIM = 4096;   // N_OUT
constexpr float QBf = 128.0f;
constexpr float EPf = 0.01f;
constexpr float LN_EPSf = 1e-5f;

#define GLOAD_LDS16(gp, lp)                                                  \
    __builtin_amdgcn_global_load_lds(                                        \
        (const __attribute__((address_space(1))) void*)(gp),                 \
        (__attribute__((address_space(3))) void*)(lp), 16, 0, 0)

#define BARRIER()                                                            \
    do { asm volatile("" ::: "memory");                                      \
         __builtin_amdgcn_s_barrier();                                       \
         asm volatile("" ::: "memory"); } while (0)

#define WAIT_LGKM(N)                                                         \
    do { asm volatile("s_waitcnt lgkmcnt(" #N ")" ::: "memory");             \
         __builtin_amdgcn_sched_barrier(0); } while (0)

#define FENCE() __builtin_amdgcn_sched_barrier(0)

// ---------------------------------------------------------------------------
// Kernel 1 (fused prep): blocks [0, M) do LayerNorm+quant rows;
// blocks [M, M+4096) do w -> int8 in MFMA-FRAGMENT order:
//   wq[((n32*128 + k32)*64 + lane)*16 + byte], lane = ((k>>4)&1)*32 + (n&31),
//   byte = k&15.  A wave's B-frag load in the GEMM is then ONE coalesced
//   1 KB global_load_dwordx4 (L2-hot) -- B never touches LDS.
// ---------------------------------------------------------------------------
__global__ __launch_bounds__(256) void prep_kernel(
    const float* __restrict__ x,
    const float* __restrict__ w,
    const float* __restrict__ ln_g,
    const float* __restrict__ ln_b,
    const float* __restrict__ gamma_p,
    char* __restrict__ xq,
    char* __restrict__ wq,
    int M)
{
    const int t = threadIdx.x;

    if ((int)blockIdx.x < M) {
        // ---------------- LayerNorm + ABSMax quant + int8 ----------------
        const int row = blockIdx.x;
        const float4* xr4 =
            reinterpret_cast<const float4*>(x + (size_t)row * K_DIM);

        float4 v[4];
        float sum = 0.f, sumsq = 0.f;
#pragma unroll
        for (int i = 0; i < 4; ++i) {
            v[i] = xr4[t * 4 + i];
            sum += v[i].x + v[i].y + v[i].z + v[i].w;
            sumsq += v[i].x * v[i].x + v[i].y * v[i].y
                   + v[i].z * v[i].z + v[i].w * v[i].w;
        }
#pragma unroll
        for (int off = 32; off > 0; off >>= 1) {
            sum += __shfl_down(sum, off);
            sumsq += __shfl_down(sumsq, off);
        }
        __shared__ float s_sum[4], s_sq[4];
        const int lane = t & 63, wv = t >> 6;
        if (lane == 0) { s_sum[wv] = sum; s_sq[wv] = sumsq; }
        __syncthreads();
        sum = s_sum[0] + s_sum[1] + s_sum[2] + s_sum[3];
        sumsq = s_sq[0] + s_sq[1] + s_sq[2] + s_sq[3];

        const float mu = sum * (1.0f / K_DIM);
        const float var = sumsq * (1.0f / K_DIM) - mu * mu;
        const float rstd = rsqrtf(var + LN_EPSf);
        const float qs = QBf / gamma_p[0];
        const float lo = -QBf + EPf, hi = QBf - EPf;

        alignas(16) char ob[16];
#pragma unroll
        for (int i = 0; i < 4; ++i) {
            const float4 g = reinterpret_cast<const float4*>(ln_g)[t * 4 + i];
            const float4 b = reinterpret_cast<const float4*>(ln_b)[t * 4 + i];
            const float f0 = fminf(fmaxf(((v[i].x - mu) * rstd * g.x + b.x) * qs, lo), hi);
            const float f1 = fminf(fmaxf(((v[i].y - mu) * rstd * g.y + b.y) * qs, lo), hi);
            const float f2 = fminf(fmaxf(((v[i].z - mu) * rstd * g.z + b.z) * qs, lo), hi);
            const float f3 = fminf(fmaxf(((v[i].w - mu) * rstd * g.w + b.w) * qs, lo), hi);
            int x0 = (int)rintf(f0), x1 = (int)rintf(f1);
            int x2 = (int)rintf(f2), x3 = (int)rintf(f3);
            ob[i * 4 + 0] = (char)(x0 > 127 ? 127 : x0);
            ob[i * 4 + 1] = (char)(x1 > 127 ? 127 : x1);
            ob[i * 4 + 2] = (char)(x2 > 127 ? 127 : x2);
            ob[i * 4 + 3] = (char)(x3 > 127 ? 127 : x3);
        }
        *reinterpret_cast<uint4*>(xq + (size_t)row * K_DIM + t * 16) =
            *reinterpret_cast<const uint4*>(ob);
    } else {
        // ------ w (fp32, K x N, ±1) -> wq (int8, fragment order) ---------
        __shared__ char tile[64][68];
        const int bidx = blockIdx.x - M;            // 0..4095
        const int bk = (bidx >> 6) * 64;            // k tile base
        const int bn = (bidx & 63) * 64;            // n tile base
#pragma unroll
        for (int i = 0; i < 4; ++i) {
            const int li = i * 1024 + t * 4;
            const int r = li >> 6, c = li & 63;     // r=k-in-tile, c=n-in-tile
            const float4 vv = *reinterpret_cast<const float4*>(
                w + (size_t)(bk + r) * N_DIM + bn + c);
            tile[r][c]     = (char)vv.x;
            tile[r][c + 1] = (char)vv.y;
            tile[r][c + 2] = (char)vv.z;
            tile[r][c + 3] = (char)vv.w;
        }
        __syncthreads();
        const int n = t >> 2, kc = t & 3;           // n 0..63, kc 0..3
        alignas(16) char h16[16];
#pragma unroll
        for (int j = 0; j < 16; ++j) h16[j] = tile[kc * 16 + j][n];
        const int gn = bn + n;
        const int gk = bk + kc * 16;                // 16-aligned
        const int n32 = gn >> 5;
        const int k32 = gk >> 5;
        const int l   = ((gk >> 4) & 1) * 32 + (gn & 31);
        *reinterpret_cast<uint4*>(
            wq + ((size_t)(n32 * (K_DIM / 32) + k32) * 64 + l) * 16) =
            *reinterpret_cast<const uint4*>(h16);
    }
}

// ---------------------------------------------------------------------------
// Kernel 2: GEMM  C[M,N] = A[M,K] * B^T * scale  (i8 MFMA, i32 acc)
// 256x256 tile, BK=128 (32 K-tiles), 512 threads = 8 waves (2M x 4N),
// wave tile 128x64 (4 mf x 2 nf x 4 ks = 32 mfma_i32_32x32x32_i8 / K-tile).
// B-DIRECT: B frags come straight from global (fragment-order wq, L2-hot)
// as 8 coalesced 1KB loads per wave per tile, issued at p7 of the PREVIOUS
// tile (full-tile latency cover; compiler inserts precise vmcnt for the
// reg RAW deps).  B never touches LDS -> BAR#1 deleted, B ds_reads deleted,
// post-barrier critical path = 2 A ds_reads.
// A side: R11's proven thin lgkm(2) chain + 2-buf LDS (64 KiB total),
// [kc][row][16B] planes, linear gload_lds dest, zero bank conflicts.
// Per K-tile (8 phases, ONE barrier):
//   R0: A(ks0,mf01)
//   p0: A(ks0,mf23) | STAGE_A(t+1)->buf^1 | lgkm(2) | MFMA(ks0,mf01)
//   p1..p6: 2 A reads | lgkm(2) | 4 MFMA   (ks walks 0..3, mf pairs)
//   p7: lgkm(0) | MFMA(ks3,mf23) | issue B(t+1) x8 | vmcnt(8) | BARRIER
// vmcnt(8) at end: FIFO [.., A(t+1)x4, B(t+1)x8] -> forces A(t+1) landed
// (publish), leaves B(t+1) flying.  WAR on buf^1: its readers completed
// before the previous tile's barrier.  Tail tile: no stage/issue, vmcnt(0).
// ---------------------------------------------------------------------------
__global__ __launch_bounds__(512, 2) void gemm_kernel(
    const char* __restrict__ A,
    const char* __restrict__ Bt,
    float* __restrict__ C,
    const float* __restrict__ beta_p,
    const float* __restrict__ gamma_p)
{
    constexpr int NT = K_DIM / 128;                // 32 K-tiles
    __shared__ __align__(16) char lds[65536];      // A only: 2 bufs x 32K

    const int t = threadIdx.x;
    // ---- XCD swizzle: flat id -> 8x8 square per XCD (512 blocks, 16x32 grid)
    const int flat = blockIdx.y * gridDim.x + blockIdx.x;
    const int xcd = flat & 7;
    const int r8 = flat >> 3;                       // 0..63
    const int by = ((xcd >> 1) << 3) + (r8 >> 3);   // 0..31  (M index)
    const int bx = ((xcd & 1) << 3) + (r8 & 7);     // 0..15  (N index)
    const int bm = by * 256;
    const int bn = bx * 256;

    const int lane = t & 63;
    const int w = t >> 6;
    const int wm = w >> 2;            // 0..1
    const int wn = w & 3;             // 0..3
    const int ln31 = lane & 31;
    const int lg2 = lane >> 5;        // 0..1

    const char* gA = A + (size_t)bm * K_DIM;
    // staging: thread t covers row (t&127), k-chunk (t>>7); 2 row-halves
    const int voff = (t & 127) * K_DIM + ((t >> 7) << 4);

    // A fragment read offset ([kc][row][16B], plane 2048; kc = ks*2+lg2)
    const int aoff = lg2 * 2048 + (ln31 << 4);

    // B direct bases (fragment-order wq): n32 = bn/32 + wn*2 + nf
    const char* gB0 = Bt + ((size_t)((bn >> 5) + wn * 2)     * 128) * 1024
                         + (size_t)lane * 16;
    const char* gB1 = Bt + ((size_t)((bn >> 5) + wn * 2 + 1) * 128) * 1024
                         + (size_t)lane * 16;

// stage one 256x128 A tile (4 x 16B/thread): row-halves at +0/+16384,
// kc 0-3 / 4-7 at +0/+8192
#define STAGE_A(b, kt)                                                        \
    do {                                                                      \
        GLOAD_LDS16(gA + (size_t)(kt) * 128 + voff,                           \
                    lds + (b) * 32768 + t * 16);                              \
        GLOAD_LDS16(gA + (size_t)(kt) * 128 + voff + 64,                      \
                    lds + (b) * 32768 + 8192 + t * 16);                       \
        GLOAD_LDS16(gA + (size_t)(128 * K_DIM) + (size_t)(kt) * 128 + voff,   \
                    lds + (b) * 32768 + 16384 + t * 16);                      \
        GLOAD_LDS16(gA + (size_t)(128 * K_DIM) + (size_t)(kt) * 128 + voff    \
                        + 64,                                                 \
                    lds + (b) * 32768 + 16384 + 8192 + t * 16);               \
    } while (0)

#define LD(p) (*reinterpret_cast<const i32x4*>(p))

#define READ_A(par, ks, mfp)                                                  \
    do {                                                                      \
        afr[par][0] = LD(ab + (ks) * 4096 + (mfp) * 1024 + aoff);             \
        afr[par][1] = LD(ab + (ks) * 4096 + (mfp) * 1024 + 512 + aoff);       \
    } while (0)

#define READ_B(kt1)                                                           \
    do {                                                                      \
        _Pragma("unroll")                                                     \
        for (int ks = 0; ks < 4; ++ks) {                                      \
            bfrag[ks][0] = LD(gB0 + (size_t)(kt1) * 4096 + ks * 1024);        \
            bfrag[ks][1] = LD(gB1 + (size_t)(kt1) * 4096 + ks * 1024);        \
        }                                                                     \
    } while (0)

#define MFMA4(par, ks, mfp)                                                   \
    do {                                                                      \
        __builtin_amdgcn_s_setprio(1);                                        \
        _Pragma("unroll")                                                     \
        for (int m2 = 0; m2 < 2; ++m2)                                        \
            _Pragma("unroll")                                                 \
            for (int nf = 0; nf < 2; ++nf)                                    \
                acc[(mfp) * 2 + m2][nf] =                                     \
                    __builtin_amdgcn_mfma_i32_32x32x32_i8(                    \
                        afr[par][m2], bfrag[ks][nf],                          \
                        acc[(mfp) * 2 + m2][nf], 0, 0, 0);                    \
        __builtin_amdgcn_s_setprio(0);                                        \
    } while (0)

// STA: stage A(t+1); RDB: issue B(t+1); VM: end-of-tile vmcnt immediate
#define TILE(b, tt, STA, RDB, VM)                                             \
    do {                                                                      \
        const char* ab = lds + (b) * 32768 + wm * 16384;                      \
        READ_A(0, 0, 0);                                                      \
        FENCE();                                                              \
        /* p0 */ READ_A(1, 0, 1);                                             \
        if (STA) STAGE_A((b) ^ 1, (tt) + 1);                                  \
        WAIT_LGKM(2); MFMA4(0, 0, 0);                                         \
        /* p1 */ READ_A(0, 1, 0); WAIT_LGKM(2); MFMA4(1, 0, 1);               \
        /* p2 */ READ_A(1, 1, 1); WAIT_LGKM(2); MFMA4(0, 1, 0);               \
        /* p3 */ READ_A(0, 2, 0); WAIT_LGKM(2); MFMA4(1, 1, 1);               \
        /* p4 */ READ_A(1, 2, 1); WAIT_LGKM(2); MFMA4(0, 2, 0);               \
        /* p5 */ READ_A(0, 3, 0); WAIT_LGKM(2); MFMA4(1, 2, 1);               \
        /* p6 */ READ_A(1, 3, 1); WAIT_LGKM(2); MFMA4(0, 3, 0);               \
        /* p7 */ WAIT_LGKM(0); MFMA4(1, 3, 1);                                \
        if (RDB) READ_B((tt) + 1);                                            \
        asm volatile("s_waitcnt vmcnt(" #VM ")" ::: "memory");                \
        BARRIER();                                                            \
    } while (0)

    i32x16 acc[4][2];
#pragma unroll
    for (int m = 0; m < 4; ++m)
#pragma unroll
        for (int n = 0; n < 2; ++n)
#pragma unroll
            for (int q = 0; q < 16; ++q)
                acc[m][n][q] = 0;

    i32x4 afr[2][2];      // [parity][m2]
    i32x4 bfrag[4][2];    // [ks][nf] -- persists across tiles

    // prologue: A(0)->buf0 (4 gloads), B(0) regs (8 loads);
    // vmcnt(8) forces A(0) landed, leaves B(0) flying; sync
    STAGE_A(0, 0);
    READ_B(0);
    asm volatile("s_waitcnt vmcnt(8)" ::: "memory");
    BARRIER();

    // tiles 0..29 full; tail 30 (stage+read 31), 31 (compute only)
    for (int kt = 0; kt < NT - 2; kt += 2) {
        TILE(0, kt, 1, 1, 8);
        TILE(1, kt + 1, 1, 1, 8);
    }
    TILE(0, NT - 2, 1, 1, 8);
    TILE(1, NT - 1, 0, 0, 0);

    // ---- epilogue: 32x32 C/D layout: col=lane&31,
    //      row = (reg&3) + 8*(reg>>2) + 4*(lane>>5) ----
    const float scale = beta_p[0] * gamma_p[0] * (1.0f / QBf);
    const int orow0 = bm + wm * 128 + lg2 * 4;
    const int ocol0 = bn + wn * 64 + ln31;
#pragma unroll
    for (int mf = 0; mf < 4; ++mf) {
#pragma unroll
        for (int nf = 0; nf < 2; ++nf) {
#pragma unroll
            for (int reg = 0; reg < 16; ++reg) {
                const int row = orow0 + mf * 32 + (reg & 3) + 8 * (reg >> 2);
                C[(size_t)row * N_DIM + ocol0 + nf * 32] =
                    (float)acc[mf][nf][reg] * scale;
            }
        }
    }
#undef STAGE_A
#undef LD
#undef READ_A
#undef READ_B
#undef MFMA4
#undef TILE
}

// ---------------------------------------------------------------------------
extern "C" void kernel_launch(void* const* d_in, const int* in_sizes, int n_in,
                              void* d_out, int out_size, void* d_ws, size_t ws_size,
                              hipStream_t stream)
{
    const float* x       = (const float*)d_in[0];
    const float* w       = (const float*)d_in[1];
    const float* ln_g    = (const float*)d_in[2];
    const float* ln_b    = (const float*)d_in[3];
    const float* beta_p  = (const float*)d_in[4];
    const float* gamma_p = (const float*)d_in[5];
    float* out = (float*)d_out;

    const int M = in_sizes[0] / K_DIM;   // 8192

    char* xq = (char*)d_ws;
    char* wq = (char*)d_ws + (size_t)M * K_DIM;

    prep_kernel<<<M + (K_DIM / 64) * (N_DIM / 64), 256, 0, stream>>>(
        x, w, ln_g, ln_b, gamma_p, xq, wq, M);
    gemm_kernel<<<dim3(N_DIM / 256, M / 256), 512, 0, stream>>>(
        xq, wq, out, beta_p, gamma_p);
}

// Round 19
// 212.584 us; speedup vs baseline: 1.0243x; 1.0243x over previous
//
#include <hip/hip_runtime.h>

using i32x4  = __attribute__((ext_vector_type(4))) int;
using i32x16 = __attribute__((ext_vector_type(16))) int;

constexpr int K_DIM = 4096;   // N_IN
constexpr int N_DIM = 4096;   // N_OUT
constexpr float QBf = 128.0f;
constexpr float EPf = 0.01f;
constexpr float LN_EPSf = 1e-5f;

#define GLOAD_LDS16(gp, lp)                                                  \
    __builtin_amdgcn_global_load_lds(                                        \
        (const __attribute__((address_space(1))) void*)(gp),                 \
        (__attribute__((address_space(3))) void*)(lp), 16, 0, 0)

#define BARRIER()                                                            \
    do { asm volatile("" ::: "memory");                                      \
         __builtin_amdgcn_s_barrier();                                       \
         asm volatile("" ::: "memory"); } while (0)

#define WAIT_LGKM(N)                                                         \
    do { asm volatile("s_waitcnt lgkmcnt(" #N ")" ::: "memory");             \
         __builtin_amdgcn_sched_barrier(0); } while (0)

#define FENCE() __builtin_amdgcn_sched_barrier(0)

// ---------------------------------------------------------------------------
// Kernel 1 (fused prep): blocks [0, M) do LayerNorm+quant rows;
// blocks [M, M+4096) do the w -> int8 N x K transpose (64x64 tiles).
// ---------------------------------------------------------------------------
__global__ __launch_bounds__(256) void prep_kernel(
    const float* __restrict__ x,
    const float* __restrict__ w,
    const float* __restrict__ ln_g,
    const float* __restrict__ ln_b,
    const float* __restrict__ gamma_p,
    char* __restrict__ xq,
    char* __restrict__ wq,
    int M)
{
    const int t = threadIdx.x;

    if ((int)blockIdx.x < M) {
        // ---------------- LayerNorm + ABSMax quant + int8 ----------------
        const int row = blockIdx.x;
        const float4* xr4 =
            reinterpret_cast<const float4*>(x + (size_t)row * K_DIM);

        float4 v[4];
        float sum = 0.f, sumsq = 0.f;
#pragma unroll
        for (int i = 0; i < 4; ++i) {
            v[i] = xr4[t * 4 + i];
            sum += v[i].x + v[i].y + v[i].z + v[i].w;
            sumsq += v[i].x * v[i].x + v[i].y * v[i].y
                   + v[i].z * v[i].z + v[i].w * v[i].w;
        }
#pragma unroll
        for (int off = 32; off > 0; off >>= 1) {
            sum += __shfl_down(sum, off);
            sumsq += __shfl_down(sumsq, off);
        }
        __shared__ float s_sum[4], s_sq[4];
        const int lane = t & 63, wv = t >> 6;
        if (lane == 0) { s_sum[wv] = sum; s_sq[wv] = sumsq; }
        __syncthreads();
        sum = s_sum[0] + s_sum[1] + s_sum[2] + s_sum[3];
        sumsq = s_sq[0] + s_sq[1] + s_sq[2] + s_sq[3];

        const float mu = sum * (1.0f / K_DIM);
        const float var = sumsq * (1.0f / K_DIM) - mu * mu;
        const float rstd = rsqrtf(var + LN_EPSf);
        const float qs = QBf / gamma_p[0];
        const float lo = -QBf + EPf, hi = QBf - EPf;

        alignas(16) char ob[16];
#pragma unroll
        for (int i = 0; i < 4; ++i) {
            const float4 g = reinterpret_cast<const float4*>(ln_g)[t * 4 + i];
            const float4 b = reinterpret_cast<const float4*>(ln_b)[t * 4 + i];
            const float f0 = fminf(fmaxf(((v[i].x - mu) * rstd * g.x + b.x) * qs, lo), hi);
            const float f1 = fminf(fmaxf(((v[i].y - mu) * rstd * g.y + b.y) * qs, lo), hi);
            const float f2 = fminf(fmaxf(((v[i].z - mu) * rstd * g.z + b.z) * qs, lo), hi);
            const float f3 = fminf(fmaxf(((v[i].w - mu) * rstd * g.w + b.w) * qs, lo), hi);
            int x0 = (int)rintf(f0), x1 = (int)rintf(f1);
            int x2 = (int)rintf(f2), x3 = (int)rintf(f3);
            ob[i * 4 + 0] = (char)(x0 > 127 ? 127 : x0);
            ob[i * 4 + 1] = (char)(x1 > 127 ? 127 : x1);
            ob[i * 4 + 2] = (char)(x2 > 127 ? 127 : x2);
            ob[i * 4 + 3] = (char)(x3 > 127 ? 127 : x3);
        }
        *reinterpret_cast<uint4*>(xq + (size_t)row * K_DIM + t * 16) =
            *reinterpret_cast<const uint4*>(ob);
    } else {
        // ---------------- w (fp32, K x N, ±1) -> wq (int8, N x K) --------
        __shared__ char tile[64][68];
        const int bidx = blockIdx.x - M;            // 0..4095
        const int bk = (bidx >> 6) * 64;            // k tile base
        const int bn = (bidx & 63) * 64;            // n tile base
#pragma unroll
        for (int i = 0; i < 4; ++i) {
            const int li = i * 1024 + t * 4;
            const int r = li >> 6, c = li & 63;     // r=k-in-tile, c=n-in-tile
            const float4 vv = *reinterpret_cast<const float4*>(
                w + (size_t)(bk + r) * N_DIM + bn + c);
            tile[r][c]     = (char)vv.x;
            tile[r][c + 1] = (char)vv.y;
            tile[r][c + 2] = (char)vv.z;
            tile[r][c + 3] = (char)vv.w;
        }
        __syncthreads();
        const int n = t >> 2, kc = t & 3;
        alignas(16) char h16[16];
#pragma unroll
        for (int j = 0; j < 16; ++j) h16[j] = tile[kc * 16 + j][n];
        *reinterpret_cast<uint4*>(wq + (size_t)(bn + n) * K_DIM + bk + kc * 16) =
            *reinterpret_cast<const uint4*>(h16);
    }
}

// ---------------------------------------------------------------------------
// Kernel 2: GEMM  C[M,N] = A[M,K] * Bt[N,K]^T * scale  (i8 MFMA, i32 acc)
// == R11 structure (measured best 173 us, confirmed 3x), setprio REMOVED ==
// (m190: s_setprio is ~0 to negative on barrier-lockstep GEMM; this kernel
// toggled it 16x/K-tile -- final ablation of the one untested component.)
// 256x256 tile, BK=128 bytes (32 K-tiles), 512 threads = 8 waves (2M x 4N),
// wave tile 128x64 (4 mf x 2 nf of mfma_i32_32x32x32_i8, 4 k-steps/K-tile).
// LDS 2 bufs x (A 32K | B 32K) = 128 KiB; per 128-row half [kc][row][16B];
// staging dest linear in t; 32-lane frag reads = 512 contiguous bytes ->
// zero bank conflicts.
// Per K-tile (8 phases, 2 barriers):
//   R0: 8 B reads (all nf,ks) + A(ks0,mf01) | FENCE
//   p0: A(ks0,mf23) | STAGE_A(t+1)->buf^1 | lgkm(2) | MFMA(ks0,mf01)
//   p1: A(ks1,mf01)                       | lgkm(2) | MFMA(ks0,mf23)
//   p2: A(ks1,mf23)                       | lgkm(2) | MFMA(ks1,mf01)
//   p3: A(ks2,mf01)                       | lgkm(2) | MFMA(ks1,mf23) | BAR#1
//   p4: A(ks2,mf23) | STAGE_B(t+2)->buf   | lgkm(2) | MFMA(ks2,mf01)
//   p5: A(ks3,mf01)                       | lgkm(2) | MFMA(ks2,mf23)
//   p6: A(ks3,mf23)                       | lgkm(2) | MFMA(ks3,mf01)
//   p7:                                     lgkm(0) | MFMA(ks3,mf23)
//       | vmcnt(4) [forces A(t+1)+B(t+1), leaves B(t+2) flying] | BAR#2
// WAR: A(t+1)->buf^1 safe (readers done before prev BAR#2); B(t+2) into the
// live buf safe after BAR#1.  Tail: vmcnt(0).
// ---------------------------------------------------------------------------
__global__ __launch_bounds__(512, 2) void gemm_kernel(
    const char* __restrict__ A,
    const char* __restrict__ Bt,
    float* __restrict__ C,
    const float* __restrict__ beta_p,
    const float* __restrict__ gamma_p)
{
    constexpr int NT = K_DIM / 128;                // 32 K-tiles
    __shared__ __align__(16) char lds[131072];     // 2 bufs x (A 32K | B 32K)

    const int t = threadIdx.x;
    // ---- XCD swizzle: flat id -> 8x8 square per XCD (512 blocks, 16x32 grid)
    const int flat = blockIdx.y * gridDim.x + blockIdx.x;
    const int xcd = flat & 7;
    const int r8 = flat >> 3;                       // 0..63
    const int by = ((xcd >> 1) << 3) + (r8 >> 3);   // 0..31  (M index)
    const int bx = ((xcd & 1) << 3) + (r8 & 7);     // 0..15  (N index)
    const int bm = by * 256;
    const int bn = bx * 256;

    const int lane = t & 63;
    const int w = t >> 6;
    const int wm = w >> 2;            // 0..1
    const int wn = w & 3;             // 0..3
    const int ln31 = lane & 31;
    const int lg2 = lane >> 5;        // 0..1

    const char* gA = A + (size_t)bm * K_DIM;
    const char* gB = Bt + (size_t)bn * K_DIM;
    // staging: thread t covers row (t&127), k-chunk (t>>7); 2 passes/half
    const int voff = (t & 127) * K_DIM + ((t >> 7) << 4);

    // fragment read offsets
    const int aoff = lg2 * 2048 + (ln31 << 4);
    const int boff = lg2 * 2048 + (((wn & 1) * 64 + ln31) << 4);

// stage one 256x128 operand tile (4 x 16B/thread): halves at +0/+16384,
// passes (kc 0-3 / 4-7) at +0/+8192
#define STAGE_OP(gbase, b, roff, kt)                                          \
    do {                                                                      \
        GLOAD_LDS16((gbase) + (size_t)(kt) * 128 + voff,                      \
                    lds + (b) * 65536 + (roff) + t * 16);                     \
        GLOAD_LDS16((gbase) + (size_t)(kt) * 128 + voff + 64,                 \
                    lds + (b) * 65536 + (roff) + 8192 + t * 16);              \
        GLOAD_LDS16((gbase) + (size_t)(128 * K_DIM) + (size_t)(kt) * 128      \
                        + voff,                                               \
                    lds + (b) * 65536 + (roff) + 16384 + t * 16);             \
        GLOAD_LDS16((gbase) + (size_t)(128 * K_DIM) + (size_t)(kt) * 128      \
                        + voff + 64,                                          \
                    lds + (b) * 65536 + (roff) + 16384 + 8192 + t * 16);      \
    } while (0)

#define STAGE_A(b, kt) STAGE_OP(gA, b, 0, kt)
#define STAGE_B(b, kt) STAGE_OP(gB, b, 32768, kt)

#define LD(p) (*reinterpret_cast<const i32x4*>(p))

#define READ_A(par, ks, mfp)                                                  \
    do {                                                                      \
        afr[par][0] = LD(ab + (ks) * 4096 + (mfp) * 1024 + aoff);             \
        afr[par][1] = LD(ab + (ks) * 4096 + (mfp) * 1024 + 512 + aoff);       \
    } while (0)

#define MFMA4(par, ks, mfp)                                                   \
    do {                                                                      \
        _Pragma("unroll")                                                     \
        for (int m2 = 0; m2 < 2; ++m2)                                        \
            _Pragma("unroll")                                                 \
            for (int nf = 0; nf < 2; ++nf)                                    \
                acc[(mfp) * 2 + m2][nf] =                                     \
                    __builtin_amdgcn_mfma_i32_32x32x32_i8(                    \
                        afr[par][m2], bfrag[nf][ks],                          \
                        acc[(mfp) * 2 + m2][nf], 0, 0, 0);                    \
    } while (0)

#define TILE(b, tt)                                                           \
    do {                                                                      \
        const char* ab = lds + (b) * 65536 + wm * 16384;                      \
        const char* bb = lds + (b) * 65536 + 32768 + (wn >> 1) * 16384;       \
        i32x4 bfrag[2][4];   /* [nf][ks] */                                   \
        i32x4 afr[2][2];     /* [parity][m2] */                               \
        _Pragma("unroll")                                                     \
        for (int nf = 0; nf < 2; ++nf)                                        \
            _Pragma("unroll")                                                 \
            for (int ks = 0; ks < 4; ++ks)                                    \
                bfrag[nf][ks] = LD(bb + ks * 4096 + nf * 512 + boff);         \
        READ_A(0, 0, 0);                                                      \
        FENCE();                                                              \
        /* p0 */ READ_A(1, 0, 1);                                             \
        if ((tt) + 1 < NT) STAGE_A((b) ^ 1, (tt) + 1);                        \
        WAIT_LGKM(2); MFMA4(0, 0, 0);                                         \
        /* p1 */ READ_A(0, 1, 0); WAIT_LGKM(2); MFMA4(1, 0, 1);               \
        /* p2 */ READ_A(1, 1, 1); WAIT_LGKM(2); MFMA4(0, 1, 0);               \
        /* p3 */ READ_A(0, 2, 0); WAIT_LGKM(2); MFMA4(1, 1, 1);               \
        BARRIER();                                                            \
        /* p4 */ READ_A(1, 2, 1);                                             \
        if ((tt) + 2 < NT) STAGE_B(b, (tt) + 2);                              \
        WAIT_LGKM(2); MFMA4(0, 2, 0);                                         \
        /* p5 */ READ_A(0, 3, 0); WAIT_LGKM(2); MFMA4(1, 2, 1);               \
        /* p6 */ READ_A(1, 3, 1); WAIT_LGKM(2); MFMA4(0, 3, 0);               \
        /* p7 */ WAIT_LGKM(0); MFMA4(1, 3, 1);                                \
        if ((tt) + 2 < NT) asm volatile("s_waitcnt vmcnt(4)" ::: "memory");   \
        else               asm volatile("s_waitcnt vmcnt(0)" ::: "memory");   \
        BARRIER();                                                            \
    } while (0)

    i32x16 acc[4][2];
#pragma unroll
    for (int m = 0; m < 4; ++m)
#pragma unroll
        for (int n = 0; n < 2; ++n)
#pragma unroll
            for (int q = 0; q < 16; ++q)
                acc[m][n][q] = 0;

    // prologue: A(0),B(0)->buf0; B(1)->buf1; force A(0),B(0); sync
    STAGE_A(0, 0); STAGE_B(0, 0); STAGE_B(1, 1);
    asm volatile("s_waitcnt vmcnt(4)" ::: "memory");
    BARRIER();

    for (int kt = 0; kt < NT; kt += 2) {
        TILE(0, kt);
        TILE(1, kt + 1);
    }

    // ---- epilogue: 32x32 C/D layout: col=lane&31,
    //      row = (reg&3) + 8*(reg>>2) + 4*(lane>>5) ----
    const float scale = beta_p[0] * gamma_p[0] * (1.0f / QBf);
    const int orow0 = bm + wm * 128 + lg2 * 4;
    const int ocol0 = bn + wn * 64 + ln31;
#pragma unroll
    for (int mf = 0; mf < 4; ++mf) {
#pragma unroll
        for (int nf = 0; nf < 2; ++nf) {
#pragma unroll
            for (int reg = 0; reg < 16; ++reg) {
                const int row = orow0 + mf * 32 + (reg & 3) + 8 * (reg >> 2);
                C[(size_t)row * N_DIM + ocol0 + nf * 32] =
                    (float)acc[mf][nf][reg] * scale;
            }
        }
    }
#undef STAGE_OP
#undef STAGE_A
#undef STAGE_B
#undef LD
#undef READ_A
#undef MFMA4
#undef TILE
}

// ---------------------------------------------------------------------------
extern "C" void kernel_launch(void* const* d_in, const int* in_sizes, int n_in,
                              void* d_out, int out_size, void* d_ws, size_t ws_size,
                              hipStream_t stream)
{
    const float* x       = (const float*)d_in[0];
    const float* w       = (const float*)d_in[1];
    const float* ln_g    = (const float*)d_in[2];
    const float* ln_b    = (const float*)d_in[3];
    const float* beta_p  = (const float*)d_in[4];
    const float* gamma_p = (const float*)d_in[5];
    float* out = (float*)d_out;

    const int M = in_sizes[0] / K_DIM;   // 8192

    char* xq = (char*)d_ws;
    char* wq = (char*)d_ws + (size_t)M * K_DIM;

    prep_kernel<<<M + (K_DIM / 64) * (N_DIM / 64), 256, 0, stream>>>(
        x, w, ln_g, ln_b, gamma_p, xq, wq, M);
    gemm_kernel<<<dim3(N_DIM / 256, M / 256), 512, 0, stream>>>(
        xq, wq, out, beta_p, gamma_p);
}